// Round 2
// baseline (815.818 us; speedup 1.0000x reference)
//
#include <hip/hip_runtime.h>

// ---------------------------------------------------------------------------
// CausalSelfAttention on MI355X (gfx950), bf16 MFMA pipeline.
// Shapes: B=4, T=2048, C=2048, H=16, D=128. N_qkv=6144.
// d_out = [ out f32 (B,T,C) | k f32 (B,H,T,D) | v f32 (B,H,T,D) ]
// ---------------------------------------------------------------------------

typedef __attribute__((ext_vector_type(4))) float f32x4;
typedef __attribute__((ext_vector_type(8))) __bf16 bf16x8;
typedef __attribute__((ext_vector_type(4))) unsigned short us4;

__device__ __forceinline__ unsigned short f2bf(float f) {
  unsigned u = __float_as_uint(f);
  u += 0x7FFFu + ((u >> 16) & 1u);   // round-to-nearest-even
  return (unsigned short)(u >> 16);
}

__device__ __forceinline__ void gl_lds16(const void* g, void* l) {
  // async global->LDS, 16B per lane; LDS dest must be uniform-base + lane*16
  __builtin_amdgcn_global_load_lds(
      (const __attribute__((address_space(1))) void*)g,
      (__attribute__((address_space(3))) void*)l, 16, 0, 0);
}

__device__ __forceinline__ f32x4 mfma_bf16(bf16x8 a, bf16x8 b, f32x4 c) {
  return __builtin_amdgcn_mfma_f32_16x16x32_bf16(a, b, c, 0, 0, 0);
}

// ---------------------------------------------------------------------------
// Prep kernels
// ---------------------------------------------------------------------------

__global__ __launch_bounds__(256) void rope_table_kernel(float* __restrict__ cos_t,
                                                         float* __restrict__ sin_t) {
  int idx = blockIdx.x * 256 + threadIdx.x;   // 131072 entries
  int t = idx >> 6, i = idx & 63;
  float freq = __expf(-(float)i * 0.14391156831212787f);  // 10000^(-i/64)
  float ang = (float)t * freq;
  float s, c;
  sincosf(ang, &s, &c);
  cos_t[idx] = c;
  sin_t[idx] = s;
}

__global__ __launch_bounds__(256) void conv_bf16_kernel(const float* __restrict__ in,
                                                        unsigned short* __restrict__ out,
                                                        int n4) {
  int idx = blockIdx.x * 256 + threadIdx.x;
  int stride = gridDim.x * 256;
  for (; idx < n4; idx += stride) {
    float4 v = ((const float4*)in)[idx];
    us4 o;
    o[0] = f2bf(v.x); o[1] = f2bf(v.y); o[2] = f2bf(v.z); o[3] = f2bf(v.w);
    ((us4*)out)[idx] = o;
  }
}

// W [R][C] f32  ->  Wt [C][R] bf16
__global__ __launch_bounds__(256) void transpose_conv_kernel(const float* __restrict__ in,
                                                             unsigned short* __restrict__ out,
                                                             int R, int C) {
  __shared__ unsigned short tile[64][68];
  const int t = threadIdx.x;
  const int c0 = blockIdx.x * 64, r0 = blockIdx.y * 64;
  const int cq = t & 15, rr = t >> 4;
#pragma unroll
  for (int i = 0; i < 4; ++i) {
    int r = rr + i * 16;
    float4 v = *(const float4*)&in[(size_t)(r0 + r) * C + c0 + cq * 4];
    tile[r][cq * 4 + 0] = f2bf(v.x);
    tile[r][cq * 4 + 1] = f2bf(v.y);
    tile[r][cq * 4 + 2] = f2bf(v.z);
    tile[r][cq * 4 + 3] = f2bf(v.w);
  }
  __syncthreads();
#pragma unroll
  for (int ii = 0; ii < 4; ++ii) {
    int c = rr + ii * 16;
    us4 o;
#pragma unroll
    for (int jj = 0; jj < 4; ++jj) o[jj] = tile[cq * 4 + jj][c];
    *(us4*)&out[(size_t)(c0 + c) * R + r0 + cq * 4] = o;
  }
}

// v f32 [z][T][D] -> vt bf16 [z][D][T]
__global__ __launch_bounds__(256) void vtrans_kernel(const float* __restrict__ in,
                                                     unsigned short* __restrict__ out) {
  __shared__ unsigned short tile[64][68];
  const int t = threadIdx.x;
  const int t0 = blockIdx.x * 64;
  const int d0 = blockIdx.y * 64;
  const size_t zi = (size_t)blockIdx.z * 2048 * 128;
  const size_t zo = (size_t)blockIdx.z * 128 * 2048;
  const int cq = t & 15, rr = t >> 4;
#pragma unroll
  for (int i = 0; i < 4; ++i) {
    int r = rr + i * 16;
    float4 v = *(const float4*)&in[zi + (size_t)(t0 + r) * 128 + d0 + cq * 4];
    tile[r][cq * 4 + 0] = f2bf(v.x);
    tile[r][cq * 4 + 1] = f2bf(v.y);
    tile[r][cq * 4 + 2] = f2bf(v.z);
    tile[r][cq * 4 + 3] = f2bf(v.w);
  }
  __syncthreads();
#pragma unroll
  for (int ii = 0; ii < 4; ++ii) {
    int c = rr + ii * 16;
    us4 o;
#pragma unroll
    for (int jj = 0; jj < 4; ++jj) o[jj] = tile[cq * 4 + jj][c];
    *(us4*)&out[zo + (size_t)(d0 + c) * 2048 + t0 + cq * 4] = o;
  }
}

// ---------------------------------------------------------------------------
// GEMM1: qkv = x @ W_attn + b_attn, fused RoPE epilogue.
// q is additionally pre-scaled by 1/sqrt(D) (consumed only by attention).
// ---------------------------------------------------------------------------
__global__ __launch_bounds__(256) void gemm_qkv_kernel(
    const unsigned short* __restrict__ xbf, const unsigned short* __restrict__ wt,
    const float* __restrict__ bias, const float* __restrict__ cost,
    const float* __restrict__ sint, float* __restrict__ out_k,
    float* __restrict__ out_v, unsigned short* __restrict__ qbf,
    unsigned short* __restrict__ kbf) {
  __shared__ __attribute__((aligned(16))) unsigned short As[128 * 64];
  __shared__ __attribute__((aligned(16))) unsigned short Bs[128 * 64];
  const int tid = threadIdx.x;
  const int w = tid >> 6, l = tid & 63, g = l >> 4, ln = l & 15;
  const int m0 = blockIdx.x * 128;
  const int nb = blockIdx.y, n0 = nb * 128;

  f32x4 acc[2][8];
#pragma unroll
  for (int i = 0; i < 2; ++i)
#pragma unroll
    for (int j = 0; j < 8; ++j) acc[i][j] = (f32x4){0.f, 0.f, 0.f, 0.f};

  for (int k0 = 0; k0 < 2048; k0 += 64) {
#pragma unroll
    for (int i = 0; i < 4; ++i) {
      int c = i * 256 + tid;
      int row = c >> 3, slot = c & 7;
      gl_lds16(xbf + ((size_t)(m0 + row) * 2048 + k0 + ((slot ^ (row & 7)) << 3)),
               &As[c << 3]);
      gl_lds16(wt + ((size_t)(n0 + row) * 2048 + k0 + ((slot ^ (row & 7)) << 3)),
               &Bs[c << 3]);
    }
    __syncthreads();
#pragma unroll
    for (int kk = 0; kk < 2; ++kk) {
      bf16x8 av[2], bv[8];
#pragma unroll
      for (int mf = 0; mf < 2; ++mf) {
        int r = w * 32 + mf * 16 + ln;
        int cb = (kk * 64 + (g << 4)) ^ ((r & 7) << 4);
        av[mf] = *(const bf16x8*)&As[r * 64 + (cb >> 1)];
      }
#pragma unroll
      for (int nf = 0; nf < 8; ++nf) {
        int r = nf * 16 + ln;
        int cb = (kk * 64 + (g << 4)) ^ ((r & 7) << 4);
        bv[nf] = *(const bf16x8*)&Bs[r * 64 + (cb >> 1)];
      }
#pragma unroll
      for (int mf = 0; mf < 2; ++mf)
#pragma unroll
        for (int nf = 0; nf < 8; ++nf)
          acc[mf][nf] = mfma_bf16(av[mf], bv[nf], acc[mf][nf]);
    }
    __syncthreads();
  }

  const int p = nb >> 4, h = nb & 15;
  float bvv[8];
#pragma unroll
  for (int nf = 0; nf < 8; ++nf) bvv[nf] = bias[n0 + nf * 16 + ln];

  if (p == 2) {  // v
#pragma unroll
    for (int mf = 0; mf < 2; ++mf)
#pragma unroll
      for (int r = 0; r < 4; ++r) {
        int m = m0 + w * 32 + mf * 16 + g * 4 + r;
        int b = m >> 11, t = m & 2047;
        size_t base = ((size_t)(b * 16 + h) * 2048 + t) * 128;
#pragma unroll
        for (int nf = 0; nf < 8; ++nf)
          out_v[base + nf * 16 + ln] = acc[mf][nf][r] + bvv[nf];
      }
  } else {  // q or k: rope
    const float sc = 0.08838834764831845f;  // 1/sqrt(128), folded into q only
#pragma unroll
    for (int mf = 0; mf < 2; ++mf)
#pragma unroll
      for (int r = 0; r < 4; ++r) {
        int m = m0 + w * 32 + mf * 16 + g * 4 + r;
        int b = m >> 11, t = m & 2047;
        size_t base = ((size_t)(b * 16 + h) * 2048 + t) * 128;
#pragma unroll
        for (int nf = 0; nf < 4; ++nf) {
          int i = nf * 16 + ln;
          float cv = cost[t * 64 + i], sv = sint[t * 64 + i];
          float a = acc[mf][nf][r] + bvv[nf];
          float bq = acc[mf][nf + 4][r] + bvv[nf + 4];
          float lo = a * cv - bq * sv;
          float hi = bq * cv + a * sv;
          if (p == 0) {
            qbf[base + i] = f2bf(lo * sc);
            qbf[base + i + 64] = f2bf(hi * sc);
          } else {
            out_k[base + i] = lo;
            out_k[base + i + 64] = hi;
            kbf[base + i] = f2bf(lo);
            kbf[base + i + 64] = f2bf(hi);
          }
        }
      }
  }
}

// ---------------------------------------------------------------------------
// Flash attention, barrier-free: 1024 blocks x 4 waves; each wave owns 32
// q-rows, streams K/V fragments straight from global (L2-resident), and uses
// only a wave-private 4KB LDS bounce for P. No __syncthreads anywhere.
// q pre-scaled by 1/sqrt(D). XCD-swizzled z; qb heavy-first.
// ---------------------------------------------------------------------------
__global__ __launch_bounds__(256, 2) void attn_kernel(
    const unsigned short* __restrict__ qbf, const unsigned short* __restrict__ kbf,
    const unsigned short* __restrict__ vtbf, unsigned short* __restrict__ ybf) {
  __shared__ __attribute__((aligned(16))) __bf16 Ps[4][32 * 64];
  const int tid = threadIdx.x;
  const int w = tid >> 6, l = tid & 63, g = l >> 4, ln = l & 15;
  const int bid = blockIdx.x;
  const int xcd = bid & 7, slot = bid >> 3;
  const int z = xcd * 8 + (slot >> 4);      // all 16 q-blocks of a head on one XCD
  const int qb = 15 - (slot & 15);          // heavy blocks first
  const size_t zo = (size_t)z * 2048 * 128;
  const size_t zv = (size_t)z * 128 * 2048;
  const int Q0 = qb * 128 + w * 32;

  __bf16* Pw = Ps[w];

  // Q fragments, resident for the whole kernel
  bf16x8 qv[2][4];
#pragma unroll
  for (int mf = 0; mf < 2; ++mf)
#pragma unroll
    for (int kk = 0; kk < 4; ++kk)
      qv[mf][kk] = *(const bf16x8*)
          &qbf[zo + (size_t)(Q0 + mf * 16 + ln) * 128 + kk * 32 + g * 8];

  f32x4 o[2][8];
#pragma unroll
  for (int mf = 0; mf < 2; ++mf)
#pragma unroll
    for (int nf = 0; nf < 8; ++nf) o[mf][nf] = (f32x4){0.f, 0.f, 0.f, 0.f};
  float mrun[2][4], lrun[2][4];
#pragma unroll
  for (int mf = 0; mf < 2; ++mf)
#pragma unroll
    for (int r = 0; r < 4; ++r) { mrun[mf][r] = -3e38f; lrun[mf][r] = 0.f; }

  const int jlast = (Q0 + 31) >> 6;
  for (int j = 0; j <= jlast; ++j) {
    const int kv0 = j << 6;

    // S = Q K^T  (32q x 64kv per wave), K fragments straight from global
    f32x4 s[2][4];
#pragma unroll
    for (int mf = 0; mf < 2; ++mf)
#pragma unroll
      for (int nf = 0; nf < 4; ++nf) s[mf][nf] = (f32x4){0.f, 0.f, 0.f, 0.f};
#pragma unroll
    for (int kk = 0; kk < 4; ++kk) {
      bf16x8 kf[4];
#pragma unroll
      for (int nf = 0; nf < 4; ++nf)
        kf[nf] = *(const bf16x8*)
            &kbf[zo + (size_t)(kv0 + nf * 16 + ln) * 128 + kk * 32 + g * 8];
#pragma unroll
      for (int mf = 0; mf < 2; ++mf)
#pragma unroll
        for (int nf = 0; nf < 4; ++nf)
          s[mf][nf] = mfma_bf16(qv[mf][kk], kf[nf], s[mf][nf]);
    }

    // causal mask: only the wave's last tile crosses the diagonal
    if (j == jlast) {
#pragma unroll
      for (int mf = 0; mf < 2; ++mf)
#pragma unroll
        for (int nf = 0; nf < 4; ++nf)
#pragma unroll
          for (int r = 0; r < 4; ++r)
            if (kv0 + nf * 16 + ln > Q0 + mf * 16 + g * 4 + r)
              s[mf][nf][r] = -3e38f;
    }

    // row max (in-lane over nf, then 16-lane shfl tree)
    float mx[2][4];
#pragma unroll
    for (int mf = 0; mf < 2; ++mf)
#pragma unroll
      for (int r = 0; r < 4; ++r) {
        float m0 = fmaxf(fmaxf(s[mf][0][r], s[mf][1][r]),
                         fmaxf(s[mf][2][r], s[mf][3][r]));
        m0 = fmaxf(m0, __shfl_xor(m0, 1));
        m0 = fmaxf(m0, __shfl_xor(m0, 2));
        m0 = fmaxf(m0, __shfl_xor(m0, 4));
        m0 = fmaxf(m0, __shfl_xor(m0, 8));
        mx[mf][r] = m0;
      }

    // defer-max (T13): rescale only when the running max moved by > 8
    float dm = 0.f;
#pragma unroll
    for (int mf = 0; mf < 2; ++mf)
#pragma unroll
      for (int r = 0; r < 4; ++r) dm = fmaxf(dm, mx[mf][r] - mrun[mf][r]);
    if (__any(dm > 8.0f)) {
#pragma unroll
      for (int mf = 0; mf < 2; ++mf)
#pragma unroll
        for (int r = 0; r < 4; ++r) {
          float mn = fmaxf(mrun[mf][r], mx[mf][r]);
          float al = __expf(mrun[mf][r] - mn);
          mrun[mf][r] = mn;
          lrun[mf][r] *= al;
#pragma unroll
          for (int nf = 0; nf < 8; ++nf) o[mf][nf][r] *= al;
        }
    }

    // P = exp(S - m), row sums, write wave-private P to LDS (swizzled)
#pragma unroll
    for (int mf = 0; mf < 2; ++mf)
#pragma unroll
      for (int r = 0; r < 4; ++r) {
        const float m0 = mrun[mf][r];
        const int row_l = mf * 16 + g * 4 + r;
        float rs = 0.f;
#pragma unroll
        for (int nf = 0; nf < 4; ++nf) {
          float pv = __expf(s[mf][nf][r] - m0);
          rs += pv;
          int byte = ((nf * 16 + ln) << 1) ^ ((row_l & 7) << 4);
          Pw[row_l * 64 + (byte >> 1)] = (__bf16)pv;
        }
        rs += __shfl_xor(rs, 1);
        rs += __shfl_xor(rs, 2);
        rs += __shfl_xor(rs, 4);
        rs += __shfl_xor(rs, 8);
        lrun[mf][r] += rs;
      }

    // same-wave LDS fence (no cross-wave sharing -> no __syncthreads)
    asm volatile("s_waitcnt lgkmcnt(0)" ::: "memory");
    __builtin_amdgcn_sched_barrier(0);

    // O += P V  (V fragments straight from global, vt = V^T layout)
#pragma unroll
    for (int kk2 = 0; kk2 < 2; ++kk2) {
      bf16x8 pa[2];
#pragma unroll
      for (int mf = 0; mf < 2; ++mf) {
        int row_l = mf * 16 + ln;
        int byte = (kk2 * 64 + g * 16) ^ ((row_l & 7) << 4);
        pa[mf] = *(const bf16x8*)&Pw[row_l * 64 + (byte >> 1)];
      }
#pragma unroll
      for (int nf2 = 0; nf2 < 8; ++nf2) {
        bf16x8 vf = *(const bf16x8*)
            &vtbf[zv + (size_t)(nf2 * 16 + ln) * 2048 + kv0 + kk2 * 32 + g * 8];
#pragma unroll
        for (int mf = 0; mf < 2; ++mf)
          o[mf][nf2] = mfma_bf16(pa[mf], vf, o[mf][nf2]);
      }
    }
  }

  // normalize + write y in [B*T][C] layout (col = h*128 + d)
  const int b = z >> 4, h = z & 15;
#pragma unroll
  for (int mf = 0; mf < 2; ++mf)
#pragma unroll
    for (int r = 0; r < 4; ++r) {
      float inv = 1.f / lrun[mf][r];
      int t = Q0 + mf * 16 + g * 4 + r;
      size_t rb = ((size_t)b * 2048 + t) * 2048 + h * 128;
#pragma unroll
      for (int nf2 = 0; nf2 < 8; ++nf2)
        ybf[rb + nf2 * 16 + ln] = f2bf(o[mf][nf2][r] * inv);
    }
}

// ---------------------------------------------------------------------------
// GEMM2: out = y @ W_proj + b_proj (f32 out)
// ---------------------------------------------------------------------------
__global__ __launch_bounds__(256) void gemm_proj_kernel(
    const unsigned short* __restrict__ ybf, const unsigned short* __restrict__ wpt,
    const float* __restrict__ bias, float* __restrict__ out) {
  __shared__ __attribute__((aligned(16))) unsigned short As[128 * 64];
  __shared__ __attribute__((aligned(16))) unsigned short Bs[128 * 64];
  const int tid = threadIdx.x;
  const int w = tid >> 6, l = tid & 63, g = l >> 4, ln = l & 15;
  const int m0 = blockIdx.x * 128;
  const int n0 = blockIdx.y * 128;

  f32x4 acc[2][8];
#pragma unroll
  for (int i = 0; i < 2; ++i)
#pragma unroll
    for (int j = 0; j < 8; ++j) acc[i][j] = (f32x4){0.f, 0.f, 0.f, 0.f};

  for (int k0 = 0; k0 < 2048; k0 += 64) {
#pragma unroll
    for (int i = 0; i < 4; ++i) {
      int c = i * 256 + tid;
      int row = c >> 3, slot = c & 7;
      gl_lds16(ybf + ((size_t)(m0 + row) * 2048 + k0 + ((slot ^ (row & 7)) << 3)),
               &As[c << 3]);
      gl_lds16(wpt + ((size_t)(n0 + row) * 2048 + k0 + ((slot ^ (row & 7)) << 3)),
               &Bs[c << 3]);
    }
    __syncthreads();
#pragma unroll
    for (int kk = 0; kk < 2; ++kk) {
      bf16x8 av[2], bv[8];
#pragma unroll
      for (int mf = 0; mf < 2; ++mf) {
        int r = w * 32 + mf * 16 + ln;
        int cb = (kk * 64 + (g << 4)) ^ ((r & 7) << 4);
        av[mf] = *(const bf16x8*)&As[r * 64 + (cb >> 1)];
      }
#pragma unroll
      for (int nf = 0; nf < 8; ++nf) {
        int r = nf * 16 + ln;
        int cb = (kk * 64 + (g << 4)) ^ ((r & 7) << 4);
        bv[nf] = *(const bf16x8*)&Bs[r * 64 + (cb >> 1)];
      }
#pragma unroll
      for (int mf = 0; mf < 2; ++mf)
#pragma unroll
        for (int nf = 0; nf < 8; ++nf)
          acc[mf][nf] = mfma_bf16(av[mf], bv[nf], acc[mf][nf]);
    }
    __syncthreads();
  }

  float bvv[8];
#pragma unroll
  for (int nf = 0; nf < 8; ++nf) bvv[nf] = bias[n0 + nf * 16 + ln];
#pragma unroll
  for (int mf = 0; mf < 2; ++mf)
#pragma unroll
    for (int r = 0; r < 4; ++r) {
      int m = m0 + w * 32 + mf * 16 + g * 4 + r;
      size_t rb = (size_t)m * 2048 + n0;
#pragma unroll
      for (int nf = 0; nf < 8; ++nf)
        out[rb + nf * 16 + ln] = acc[mf][nf][r] + bvv[nf];
    }
}

// ---------------------------------------------------------------------------
// Launch
// ---------------------------------------------------------------------------
extern "C" void kernel_launch(void* const* d_in, const int* in_sizes, int n_in,
                              void* d_out, int out_size, void* d_ws, size_t ws_size,
                              hipStream_t stream) {
  (void)in_sizes; (void)n_in; (void)out_size; (void)ws_size;
  const float* x      = (const float*)d_in[0];
  const float* W_attn = (const float*)d_in[1];
  const float* b_attn = (const float*)d_in[2];
  const float* W_proj = (const float*)d_in[3];
  const float* b_proj = (const float*)d_in[4];

  float* out   = (float*)d_out;                 // [8192][2048]
  float* out_k = out + 16777216;                // [64][2048][128]
  float* out_v = out + 33554432;                // [64][2048][128]

  char* ws = (char*)d_ws;
  unsigned short* q_bf  = (unsigned short*)(ws + 0);           // 33.5 MB
  unsigned short* k_bf  = (unsigned short*)(ws + 33554432);    // 33.5 MB
  unsigned short* vt_bf = (unsigned short*)(ws + 67108864);    // 33.5 MB
  unsigned short* x_bf  = (unsigned short*)(ws + 100663296);   // 33.5 MB (reused as y2d)
  unsigned short* y2d   = x_bf;                                // x_bf dead after GEMM1
  unsigned short* wt    = (unsigned short*)(ws + 134217728);   // 25.2 MB
  unsigned short* wpt   = (unsigned short*)(ws + 159383552);   // 8.4 MB
  float* cos_t = (float*)(ws + 167772160);                     // 0.5 MB
  float* sin_t = (float*)(ws + 168296448);                     // 0.5 MB

  rope_table_kernel<<<512, 256, 0, stream>>>(cos_t, sin_t);
  conv_bf16_kernel<<<2048, 256, 0, stream>>>(x, x_bf, 16777216 / 4);
  transpose_conv_kernel<<<dim3(6144 / 64, 2048 / 64), 256, 0, stream>>>(W_attn, wt, 2048, 6144);
  transpose_conv_kernel<<<dim3(2048 / 64, 2048 / 64), 256, 0, stream>>>(W_proj, wpt, 2048, 2048);
  gemm_qkv_kernel<<<dim3(64, 48), 256, 0, stream>>>(x_bf, wt, b_attn, cos_t, sin_t,
                                                    out_k, out_v, q_bf, k_bf);
  vtrans_kernel<<<dim3(32, 2, 64), 256, 0, stream>>>(out_v, vt_bf);
  attn_kernel<<<1024, 256, 0, stream>>>(q_bf, k_bf, vt_bf, y2d);
  gemm_proj_kernel<<<dim3(64, 16), 256, 0, stream>>>(y2d, wpt, b_proj, out);
}

// Round 3
// 558.643 us; speedup vs baseline: 1.4604x; 1.4604x over previous
//
#include <hip/hip_runtime.h>

// ---------------------------------------------------------------------------
// CausalSelfAttention on MI355X (gfx950), bf16 MFMA pipeline.
// Shapes: B=4, T=2048, C=2048, H=16, D=128. N_qkv=6144.
// d_out = [ out f32 (B,T,C) | k f32 (B,H,T,D) | v f32 (B,H,T,D) ]
// ---------------------------------------------------------------------------

typedef __attribute__((ext_vector_type(4))) float f32x4;
typedef __attribute__((ext_vector_type(8))) __bf16 bf16x8;
typedef __attribute__((ext_vector_type(4))) unsigned short us4;

__device__ __forceinline__ unsigned short f2bf(float f) {
  unsigned u = __float_as_uint(f);
  u += 0x7FFFu + ((u >> 16) & 1u);   // round-to-nearest-even
  return (unsigned short)(u >> 16);
}

__device__ __forceinline__ void gl_lds16(const void* g, void* l) {
  // async global->LDS, 16B per lane; LDS dest must be uniform-base + lane*16
  __builtin_amdgcn_global_load_lds(
      (const __attribute__((address_space(1))) void*)g,
      (__attribute__((address_space(3))) void*)l, 16, 0, 0);
}

__device__ __forceinline__ f32x4 mfma_bf16(bf16x8 a, bf16x8 b, f32x4 c) {
  return __builtin_amdgcn_mfma_f32_16x16x32_bf16(a, b, c, 0, 0, 0);
}

// ---------------------------------------------------------------------------
// Prep kernels
// ---------------------------------------------------------------------------

__global__ __launch_bounds__(256) void rope_table_kernel(float* __restrict__ cos_t,
                                                         float* __restrict__ sin_t) {
  int idx = blockIdx.x * 256 + threadIdx.x;   // 131072 entries
  int t = idx >> 6, i = idx & 63;
  float freq = __expf(-(float)i * 0.14391156831212787f);  // 10000^(-i/64)
  float ang = (float)t * freq;
  float s, c;
  sincosf(ang, &s, &c);
  cos_t[idx] = c;
  sin_t[idx] = s;
}

__global__ __launch_bounds__(256) void conv_bf16_kernel(const float* __restrict__ in,
                                                        unsigned short* __restrict__ out,
                                                        int n4) {
  int idx = blockIdx.x * 256 + threadIdx.x;
  int stride = gridDim.x * 256;
  for (; idx < n4; idx += stride) {
    float4 v = ((const float4*)in)[idx];
    us4 o;
    o[0] = f2bf(v.x); o[1] = f2bf(v.y); o[2] = f2bf(v.z); o[3] = f2bf(v.w);
    ((us4*)out)[idx] = o;
  }
}

// W [R][C] f32  ->  Wt [C][R] bf16
__global__ __launch_bounds__(256) void transpose_conv_kernel(const float* __restrict__ in,
                                                             unsigned short* __restrict__ out,
                                                             int R, int C) {
  __shared__ unsigned short tile[64][68];
  const int t = threadIdx.x;
  const int c0 = blockIdx.x * 64, r0 = blockIdx.y * 64;
  const int cq = t & 15, rr = t >> 4;
#pragma unroll
  for (int i = 0; i < 4; ++i) {
    int r = rr + i * 16;
    float4 v = *(const float4*)&in[(size_t)(r0 + r) * C + c0 + cq * 4];
    tile[r][cq * 4 + 0] = f2bf(v.x);
    tile[r][cq * 4 + 1] = f2bf(v.y);
    tile[r][cq * 4 + 2] = f2bf(v.z);
    tile[r][cq * 4 + 3] = f2bf(v.w);
  }
  __syncthreads();
#pragma unroll
  for (int ii = 0; ii < 4; ++ii) {
    int c = rr + ii * 16;
    us4 o;
#pragma unroll
    for (int jj = 0; jj < 4; ++jj) o[jj] = tile[cq * 4 + jj][c];
    *(us4*)&out[(size_t)(c0 + c) * R + r0 + cq * 4] = o;
  }
}

// v f32 [z][T][D] -> vt bf16 [z][D][T]
__global__ __launch_bounds__(256) void vtrans_kernel(const float* __restrict__ in,
                                                     unsigned short* __restrict__ out) {
  __shared__ unsigned short tile[64][68];
  const int t = threadIdx.x;
  const int t0 = blockIdx.x * 64;
  const int d0 = blockIdx.y * 64;
  const size_t zi = (size_t)blockIdx.z * 2048 * 128;
  const size_t zo = (size_t)blockIdx.z * 128 * 2048;
  const int cq = t & 15, rr = t >> 4;
#pragma unroll
  for (int i = 0; i < 4; ++i) {
    int r = rr + i * 16;
    float4 v = *(const float4*)&in[zi + (size_t)(t0 + r) * 128 + d0 + cq * 4];
    tile[r][cq * 4 + 0] = f2bf(v.x);
    tile[r][cq * 4 + 1] = f2bf(v.y);
    tile[r][cq * 4 + 2] = f2bf(v.z);
    tile[r][cq * 4 + 3] = f2bf(v.w);
  }
  __syncthreads();
#pragma unroll
  for (int ii = 0; ii < 4; ++ii) {
    int c = rr + ii * 16;
    us4 o;
#pragma unroll
    for (int jj = 0; jj < 4; ++jj) o[jj] = tile[cq * 4 + jj][c];
    *(us4*)&out[zo + (size_t)(d0 + c) * 2048 + t0 + cq * 4] = o;
  }
}

// ---------------------------------------------------------------------------
// GEMM1: qkv = x @ W_attn + b_attn, fused RoPE epilogue.
// q is additionally pre-scaled by 1/sqrt(D) (consumed only by attention).
// ---------------------------------------------------------------------------
__global__ __launch_bounds__(256) void gemm_qkv_kernel(
    const unsigned short* __restrict__ xbf, const unsigned short* __restrict__ wt,
    const float* __restrict__ bias, const float* __restrict__ cost,
    const float* __restrict__ sint, float* __restrict__ out_k,
    float* __restrict__ out_v, unsigned short* __restrict__ qbf,
    unsigned short* __restrict__ kbf) {
  __shared__ __attribute__((aligned(16))) unsigned short As[128 * 64];
  __shared__ __attribute__((aligned(16))) unsigned short Bs[128 * 64];
  const int tid = threadIdx.x;
  const int w = tid >> 6, l = tid & 63, g = l >> 4, ln = l & 15;
  const int m0 = blockIdx.x * 128;
  const int nb = blockIdx.y, n0 = nb * 128;

  f32x4 acc[2][8];
#pragma unroll
  for (int i = 0; i < 2; ++i)
#pragma unroll
    for (int j = 0; j < 8; ++j) acc[i][j] = (f32x4){0.f, 0.f, 0.f, 0.f};

  for (int k0 = 0; k0 < 2048; k0 += 64) {
#pragma unroll
    for (int i = 0; i < 4; ++i) {
      int c = i * 256 + tid;
      int row = c >> 3, slot = c & 7;
      gl_lds16(xbf + ((size_t)(m0 + row) * 2048 + k0 + ((slot ^ (row & 7)) << 3)),
               &As[c << 3]);
      gl_lds16(wt + ((size_t)(n0 + row) * 2048 + k0 + ((slot ^ (row & 7)) << 3)),
               &Bs[c << 3]);
    }
    __syncthreads();
#pragma unroll
    for (int kk = 0; kk < 2; ++kk) {
      bf16x8 av[2], bv[8];
#pragma unroll
      for (int mf = 0; mf < 2; ++mf) {
        int r = w * 32 + mf * 16 + ln;
        int cb = (kk * 64 + (g << 4)) ^ ((r & 7) << 4);
        av[mf] = *(const bf16x8*)&As[r * 64 + (cb >> 1)];
      }
#pragma unroll
      for (int nf = 0; nf < 8; ++nf) {
        int r = nf * 16 + ln;
        int cb = (kk * 64 + (g << 4)) ^ ((r & 7) << 4);
        bv[nf] = *(const bf16x8*)&Bs[r * 64 + (cb >> 1)];
      }
#pragma unroll
      for (int mf = 0; mf < 2; ++mf)
#pragma unroll
        for (int nf = 0; nf < 8; ++nf)
          acc[mf][nf] = mfma_bf16(av[mf], bv[nf], acc[mf][nf]);
    }
    __syncthreads();
  }

  const int p = nb >> 4, h = nb & 15;
  float bvv[8];
#pragma unroll
  for (int nf = 0; nf < 8; ++nf) bvv[nf] = bias[n0 + nf * 16 + ln];

  if (p == 2) {  // v
#pragma unroll
    for (int mf = 0; mf < 2; ++mf)
#pragma unroll
      for (int r = 0; r < 4; ++r) {
        int m = m0 + w * 32 + mf * 16 + g * 4 + r;
        int b = m >> 11, t = m & 2047;
        size_t base = ((size_t)(b * 16 + h) * 2048 + t) * 128;
#pragma unroll
        for (int nf = 0; nf < 8; ++nf)
          out_v[base + nf * 16 + ln] = acc[mf][nf][r] + bvv[nf];
      }
  } else {  // q or k: rope
    const float sc = 0.08838834764831845f;  // 1/sqrt(128), folded into q only
#pragma unroll
    for (int mf = 0; mf < 2; ++mf)
#pragma unroll
      for (int r = 0; r < 4; ++r) {
        int m = m0 + w * 32 + mf * 16 + g * 4 + r;
        int b = m >> 11, t = m & 2047;
        size_t base = ((size_t)(b * 16 + h) * 2048 + t) * 128;
#pragma unroll
        for (int nf = 0; nf < 4; ++nf) {
          int i = nf * 16 + ln;
          float cv = cost[t * 64 + i], sv = sint[t * 64 + i];
          float a = acc[mf][nf][r] + bvv[nf];
          float bq = acc[mf][nf + 4][r] + bvv[nf + 4];
          float lo = a * cv - bq * sv;
          float hi = bq * cv + a * sv;
          if (p == 0) {
            qbf[base + i] = f2bf(lo * sc);
            qbf[base + i + 64] = f2bf(hi * sc);
          } else {
            out_k[base + i] = lo;
            out_k[base + i + 64] = hi;
            kbf[base + i] = f2bf(lo);
            kbf[base + i + 64] = f2bf(hi);
          }
        }
      }
  }
}

// ---------------------------------------------------------------------------
// Flash attention v3: grid 1024 = (z 64) x (qp 16). 128 q-rows per block,
// 4 waves x 32 rows. K/V tiles (64 kv) staged in LDS via global_load_lds,
// double-buffered, counted vmcnt(8) (never 0 in steady state), one barrier
// pair per tile. Shared staging amortizes K/V across the 4 waves.
// q pre-scaled by 1/sqrt(D). Heavy-first qp, XCD-affine z.
// ---------------------------------------------------------------------------
__global__ __launch_bounds__(256, 2) void attn_kernel(
    const unsigned short* __restrict__ qbf, const unsigned short* __restrict__ kbf,
    const unsigned short* __restrict__ vtbf, unsigned short* __restrict__ ybf) {
  __shared__ __attribute__((aligned(16))) unsigned short Ks[2][64 * 128];
  __shared__ __attribute__((aligned(16))) unsigned short Vs[2][128 * 64];
  __shared__ __attribute__((aligned(16))) __bf16 Ps[4][32 * 64];
  const int tid = threadIdx.x;
  const int w = tid >> 6, l = tid & 63, g = l >> 4, ln = l & 15;
  const int bid = blockIdx.x;
  const int z = (bid & 7) * 8 + ((bid >> 3) & 7);  // XCD-affine head/batch
  const int qp = 15 - (bid >> 6);                  // heavy q-panels first
  const size_t zo = (size_t)z * (2048 * 128);
  const size_t zv = (size_t)z * (128 * 2048);
  const int Q0w = qp * 128 + w * 32;
  const int jn = 2 * qp + 2;           // KV tiles this block processes
  const int jlw = 2 * qp + (w >> 1);   // this wave's diagonal (masked) tile
  __bf16* Pw = Ps[w];

  // resident Q fragments
  bf16x8 qv[2][4];
#pragma unroll
  for (int mf = 0; mf < 2; ++mf)
#pragma unroll
    for (int kk = 0; kk < 4; ++kk)
      qv[mf][kk] = *(const bf16x8*)
          &qbf[zo + (size_t)(Q0w + mf * 16 + ln) * 128 + kk * 32 + g * 8];

  f32x4 o[2][8];
#pragma unroll
  for (int mf = 0; mf < 2; ++mf)
#pragma unroll
    for (int nf = 0; nf < 8; ++nf) o[mf][nf] = (f32x4){0.f, 0.f, 0.f, 0.f};
  float mrun[2][4], lrun[2][4];
#pragma unroll
  for (int mf = 0; mf < 2; ++mf)
#pragma unroll
    for (int r = 0; r < 4; ++r) { mrun[mf][r] = -3e38f; lrun[mf][r] = 0.f; }

  // stage tile J into buffer B: 8 gl_lds16 per thread (4 K + 4 V)
#define STAGE_KV(J, B)                                                         \
  do {                                                                         \
    const int kv0_ = (J) << 6;                                                 \
    _Pragma("unroll") for (int i_ = 0; i_ < 4; ++i_) {                         \
      int c_ = i_ * 256 + tid;                                                 \
      int r_ = c_ >> 4, s_ = c_ & 15;                                          \
      gl_lds16(kbf + zo + (size_t)(kv0_ + r_) * 128 +                          \
                   (((s_ * 16) ^ ((r_ & 7) << 4)) >> 1),                       \
               &Ks[B][c_ * 8]);                                                \
    }                                                                          \
    _Pragma("unroll") for (int i_ = 0; i_ < 4; ++i_) {                         \
      int c_ = i_ * 256 + tid;                                                 \
      int d_ = c_ >> 3, s_ = c_ & 7;                                           \
      gl_lds16(vtbf + zv + (size_t)d_ * 2048 + kv0_ +                          \
                   (((s_ * 16) ^ ((d_ & 7) << 4)) >> 1),                       \
               &Vs[B][c_ * 8]);                                                \
    }                                                                          \
  } while (0)

  STAGE_KV(0, 0);
  STAGE_KV(1, 1);

  for (int j = 0; j < jn; ++j) {
    // wait for tile j's 8 loads (tile j+1's 8 stay in flight) -- counted vmcnt
    if (j + 1 < jn)
      asm volatile("s_waitcnt vmcnt(8)" ::: "memory");
    else
      asm volatile("s_waitcnt vmcnt(0)" ::: "memory");
    __builtin_amdgcn_s_barrier();
    const int bfr = j & 1;
    const unsigned short* Kb = Ks[bfr];
    const unsigned short* Vb = Vs[bfr];

    if (j <= jlw) {  // wave-uniform; beyond-diagonal tiles skipped
      const int kv0 = j << 6;

      // S = Q K^T  (32q x 64kv)
      f32x4 s[2][4];
#pragma unroll
      for (int mf = 0; mf < 2; ++mf)
#pragma unroll
        for (int nf = 0; nf < 4; ++nf) s[mf][nf] = (f32x4){0.f, 0.f, 0.f, 0.f};
#pragma unroll
      for (int kk = 0; kk < 4; ++kk) {
        bf16x8 kf[4];
#pragma unroll
        for (int nf = 0; nf < 4; ++nf) {
          int rr = nf * 16 + ln;
          kf[nf] = *(const bf16x8*)
              &Kb[rr * 128 + (((kk * 64 + g * 16) ^ ((rr & 7) << 4)) >> 1)];
        }
#pragma unroll
        for (int mf = 0; mf < 2; ++mf)
#pragma unroll
          for (int nf = 0; nf < 4; ++nf)
            s[mf][nf] = mfma_bf16(qv[mf][kk], kf[nf], s[mf][nf]);
      }

      // causal mask on the diagonal tile only
      if (j == jlw) {
#pragma unroll
        for (int mf = 0; mf < 2; ++mf)
#pragma unroll
          for (int nf = 0; nf < 4; ++nf)
#pragma unroll
            for (int r = 0; r < 4; ++r)
              if (kv0 + nf * 16 + ln > Q0w + mf * 16 + g * 4 + r)
                s[mf][nf][r] = -3e38f;
      }

      // row max
      float mx[2][4];
#pragma unroll
      for (int mf = 0; mf < 2; ++mf)
#pragma unroll
        for (int r = 0; r < 4; ++r) {
          float m0 = fmaxf(fmaxf(s[mf][0][r], s[mf][1][r]),
                           fmaxf(s[mf][2][r], s[mf][3][r]));
          m0 = fmaxf(m0, __shfl_xor(m0, 1));
          m0 = fmaxf(m0, __shfl_xor(m0, 2));
          m0 = fmaxf(m0, __shfl_xor(m0, 4));
          m0 = fmaxf(m0, __shfl_xor(m0, 8));
          mx[mf][r] = m0;
        }

      // defer-max (T13): rescale only when running max moved by > 8
      float dm = 0.f;
#pragma unroll
      for (int mf = 0; mf < 2; ++mf)
#pragma unroll
        for (int r = 0; r < 4; ++r) dm = fmaxf(dm, mx[mf][r] - mrun[mf][r]);
      if (__any(dm > 8.0f)) {
#pragma unroll
        for (int mf = 0; mf < 2; ++mf)
#pragma unroll
          for (int r = 0; r < 4; ++r) {
            float mn = fmaxf(mrun[mf][r], mx[mf][r]);
            float al = __expf(mrun[mf][r] - mn);
            mrun[mf][r] = mn;
            lrun[mf][r] *= al;
#pragma unroll
            for (int nf = 0; nf < 8; ++nf) o[mf][nf][r] *= al;
          }
      }

      // P = exp(S - m), row sums, wave-private P -> LDS (swizzled)
#pragma unroll
      for (int mf = 0; mf < 2; ++mf)
#pragma unroll
        for (int r = 0; r < 4; ++r) {
          const float m0 = mrun[mf][r];
          const int row_l = mf * 16 + g * 4 + r;
          float rs = 0.f;
#pragma unroll
          for (int nf = 0; nf < 4; ++nf) {
            float pv = __expf(s[mf][nf][r] - m0);
            rs += pv;
            int byte = ((nf * 16 + ln) << 1) ^ ((row_l & 7) << 4);
            Pw[row_l * 64 + (byte >> 1)] = (__bf16)pv;
          }
          rs += __shfl_xor(rs, 1);
          rs += __shfl_xor(rs, 2);
          rs += __shfl_xor(rs, 4);
          rs += __shfl_xor(rs, 8);
          lrun[mf][r] += rs;
        }

      // O += P V   (compiler orders Pw write->read; Vs reads are free to hoist)
#pragma unroll
      for (int kk2 = 0; kk2 < 2; ++kk2) {
        bf16x8 pa[2];
#pragma unroll
        for (int mf = 0; mf < 2; ++mf) {
          int pr = mf * 16 + ln;
          int byte = (kk2 * 64 + g * 16) ^ ((pr & 7) << 4);
          pa[mf] = *(const bf16x8*)&Pw[pr * 64 + (byte >> 1)];
        }
#pragma unroll
        for (int nf2 = 0; nf2 < 8; ++nf2) {
          int dr = nf2 * 16 + ln;
          bf16x8 vf = *(const bf16x8*)
              &Vb[dr * 64 + (((kk2 * 64 + g * 16) ^ ((dr & 7) << 4)) >> 1)];
#pragma unroll
          for (int mf = 0; mf < 2; ++mf)
            o[mf][nf2] = mfma_bf16(pa[mf], vf, o[mf][nf2]);
        }
      }
    }

    __builtin_amdgcn_s_barrier();
    __builtin_amdgcn_sched_barrier(0);
    if (j + 2 < jn) STAGE_KV(j + 2, bfr);
  }
#undef STAGE_KV

  // normalize + write y in [B*T][C] layout (col = h*128 + d)
  const int b = z >> 4, h = z & 15;
#pragma unroll
  for (int mf = 0; mf < 2; ++mf)
#pragma unroll
    for (int r = 0; r < 4; ++r) {
      float inv = 1.f / lrun[mf][r];
      int t = Q0w + mf * 16 + g * 4 + r;
      size_t rb = ((size_t)b * 2048 + t) * 2048 + h * 128;
#pragma unroll
      for (int nf2 = 0; nf2 < 8; ++nf2)
        ybf[rb + nf2 * 16 + ln] = f2bf(o[mf][nf2][r] * inv);
    }
}

// ---------------------------------------------------------------------------
// GEMM2: out = y @ W_proj + b_proj (f32 out)
// ---------------------------------------------------------------------------
__global__ __launch_bounds__(256) void gemm_proj_kernel(
    const unsigned short* __restrict__ ybf, const unsigned short* __restrict__ wpt,
    const float* __restrict__ bias, float* __restrict__ out) {
  __shared__ __attribute__((aligned(16))) unsigned short As[128 * 64];
  __shared__ __attribute__((aligned(16))) unsigned short Bs[128 * 64];
  const int tid = threadIdx.x;
  const int w = tid >> 6, l = tid & 63, g = l >> 4, ln = l & 15;
  const int m0 = blockIdx.x * 128;
  const int n0 = blockIdx.y * 128;

  f32x4 acc[2][8];
#pragma unroll
  for (int i = 0; i < 2; ++i)
#pragma unroll
    for (int j = 0; j < 8; ++j) acc[i][j] = (f32x4){0.f, 0.f, 0.f, 0.f};

  for (int k0 = 0; k0 < 2048; k0 += 64) {
#pragma unroll
    for (int i = 0; i < 4; ++i) {
      int c = i * 256 + tid;
      int row = c >> 3, slot = c & 7;
      gl_lds16(ybf + ((size_t)(m0 + row) * 2048 + k0 + ((slot ^ (row & 7)) << 3)),
               &As[c << 3]);
      gl_lds16(wpt + ((size_t)(n0 + row) * 2048 + k0 + ((slot ^ (row & 7)) << 3)),
               &Bs[c << 3]);
    }
    __syncthreads();
#pragma unroll
    for (int kk = 0; kk < 2; ++kk) {
      bf16x8 av[2], bv[8];
#pragma unroll
      for (int mf = 0; mf < 2; ++mf) {
        int r = w * 32 + mf * 16 + ln;
        int cb = (kk * 64 + (g << 4)) ^ ((r & 7) << 4);
        av[mf] = *(const bf16x8*)&As[r * 64 + (cb >> 1)];
      }
#pragma unroll
      for (int nf = 0; nf < 8; ++nf) {
        int r = nf * 16 + ln;
        int cb = (kk * 64 + (g << 4)) ^ ((r & 7) << 4);
        bv[nf] = *(const bf16x8*)&Bs[r * 64 + (cb >> 1)];
      }
#pragma unroll
      for (int mf = 0; mf < 2; ++mf)
#pragma unroll
        for (int nf = 0; nf < 8; ++nf)
          acc[mf][nf] = mfma_bf16(av[mf], bv[nf], acc[mf][nf]);
    }
    __syncthreads();
  }

  float bvv[8];
#pragma unroll
  for (int nf = 0; nf < 8; ++nf) bvv[nf] = bias[n0 + nf * 16 + ln];
#pragma unroll
  for (int mf = 0; mf < 2; ++mf)
#pragma unroll
    for (int r = 0; r < 4; ++r) {
      int m = m0 + w * 32 + mf * 16 + g * 4 + r;
      size_t rb = (size_t)m * 2048 + n0;
#pragma unroll
      for (int nf = 0; nf < 8; ++nf)
        out[rb + nf * 16 + ln] = acc[mf][nf][r] + bvv[nf];
    }
}

// ---------------------------------------------------------------------------
// Launch
// ---------------------------------------------------------------------------
extern "C" void kernel_launch(void* const* d_in, const int* in_sizes, int n_in,
                              void* d_out, int out_size, void* d_ws, size_t ws_size,
                              hipStream_t stream) {
  (void)in_sizes; (void)n_in; (void)out_size; (void)ws_size;
  const float* x      = (const float*)d_in[0];
  const float* W_attn = (const float*)d_in[1];
  const float* b_attn = (const float*)d_in[2];
  const float* W_proj = (const float*)d_in[3];
  const float* b_proj = (const float*)d_in[4];

  float* out   = (float*)d_out;                 // [8192][2048]
  float* out_k = out + 16777216;                // [64][2048][128]
  float* out_v = out + 33554432;                // [64][2048][128]

  char* ws = (char*)d_ws;
  unsigned short* q_bf  = (unsigned short*)(ws + 0);           // 33.5 MB
  unsigned short* k_bf  = (unsigned short*)(ws + 33554432);    // 33.5 MB
  unsigned short* vt_bf = (unsigned short*)(ws + 67108864);    // 33.5 MB
  unsigned short* x_bf  = (unsigned short*)(ws + 100663296);   // 33.5 MB (reused as y2d)
  unsigned short* y2d   = x_bf;                                // x_bf dead after GEMM1
  unsigned short* wt    = (unsigned short*)(ws + 134217728);   // 25.2 MB
  unsigned short* wpt   = (unsigned short*)(ws + 159383552);   // 8.4 MB
  float* cos_t = (float*)(ws + 167772160);                     // 0.5 MB
  float* sin_t = (float*)(ws + 168296448);                     // 0.5 MB

  rope_table_kernel<<<512, 256, 0, stream>>>(cos_t, sin_t);
  conv_bf16_kernel<<<2048, 256, 0, stream>>>(x, x_bf, 16777216 / 4);
  transpose_conv_kernel<<<dim3(6144 / 64, 2048 / 64), 256, 0, stream>>>(W_attn, wt, 2048, 6144);
  transpose_conv_kernel<<<dim3(2048 / 64, 2048 / 64), 256, 0, stream>>>(W_proj, wpt, 2048, 2048);
  gemm_qkv_kernel<<<dim3(64, 48), 256, 0, stream>>>(x_bf, wt, b_attn, cos_t, sin_t,
                                                    out_k, out_v, q_bf, k_bf);
  vtrans_kernel<<<dim3(32, 2, 64), 256, 0, stream>>>(out_v, vt_bf);
  attn_kernel<<<1024, 256, 0, stream>>>(q_bf, k_bf, vt_bf, y2d);
  gemm_proj_kernel<<<dim3(64, 16), 256, 0, stream>>>(y2d, wpt, b_proj, out);
}